// Round 13
// baseline (445.172 us; speedup 1.0000x reference)
//
#include <hip/hip_runtime.h>
#include <hip/hip_bf16.h>

#define D_MODEL 1024
#define D_HEAD  64
#define T_SEQ   4096
#define NB      4
#define NROWS   (NB * T_SEQ)      // 16384
#define SPLIT   8

typedef float f32x4 __attribute__((ext_vector_type(4)));
typedef __bf16 bf16x8 __attribute__((ext_vector_type(8)));
typedef unsigned short u16;
typedef unsigned u32x2 __attribute__((ext_vector_type(2)));
typedef unsigned u32x4 __attribute__((ext_vector_type(4)));

__device__ inline unsigned pk_bf16(float a, float b) {
    unsigned ua = __builtin_bit_cast(unsigned, a);
    unsigned ub = __builtin_bit_cast(unsigned, b);
    ua = (ua + 0x7FFFu + ((ua >> 16) & 1u)) >> 16;   // RNE
    ub = (ub + 0x7FFFu + ((ub >> 16) & 1u)) >> 16;
    return ua | (ub << 16);
}
__device__ inline u16 bf16r(float a) {
    unsigned ua = __builtin_bit_cast(unsigned, a);
    return (u16)((ua + 0x7FFFu + ((ua >> 16) & 1u)) >> 16);
}
// HW packed f32->bf16 (RNE), 1 inst per 2 values; no builtin on gfx950
__device__ inline unsigned cvtpk_bf16(float lo, float hi) {
    unsigned r;
    asm("v_cvt_pk_bf16_f32 %0, %1, %2" : "=v"(r) : "v"(lo), "v"(hi));
    return r;
}

// async global->LDS, 16B per lane, no VGPR staging
__device__ inline void gload_lds16(const void* g, void* l) {
    __builtin_amdgcn_global_load_lds(
        (const __attribute__((address_space(1))) void*)g,
        (__attribute__((address_space(3))) void*)l, 16, 0, 0);
}

// ---------------- W pre-pack + counter zero ------------------------------------------------
__global__ __launch_bounds__(256) void packw_kernel(
    const float* __restrict__ Wq, const float* __restrict__ Wk,
    const float* __restrict__ Wv, unsigned* __restrict__ Wpk,
    unsigned* __restrict__ Cnt)
{
    const int id = blockIdx.x * 256 + threadIdx.x;   // 0..24575
    if (id < NB * 256) Cnt[id] = 0;                  // strip completion counters
    const int kb = id / 192;
    const int n  = id - kb * 192;
    const int sel = n >> 6, col = n & 63;
    const float* W = sel == 0 ? Wq : (sel == 1 ? Wk : Wv);
    float f[8];
#pragma unroll
    for (int j = 0; j < 8; ++j) f[j] = W[(kb * 8 + j) * 64 + col];
    uint4 o;
    o.x = pk_bf16(f[0], f[1]); o.y = pk_bf16(f[2], f[3]);
    o.z = pk_bf16(f[4], f[5]); o.w = pk_bf16(f[6], f[7]);
    *(uint4*)(Wpk + (size_t)id * 4) = o;
}

// ---------------- QKV projection: R22 — async-DMA f32 staging, cvt-on-read (unchanged) ------
__global__ __launch_bounds__(256) void qkv_kernel(
    const float* __restrict__ x, const unsigned* __restrict__ Wpk,
    u16* __restrict__ Qbf, u16* __restrict__ Kbf, u16* __restrict__ Vt)
{
    __shared__ __align__(16) float Xs[2][32 * 128];     // 2 x 16 KB raw f32
    __shared__ __align__(16) u16 Vbuf[64 * 32];         // V^T bounce: [dim 64][tpos 32]

    const int tid  = threadIdx.x;
    const int w    = tid >> 6;
    const int lane = tid & 63;
    const int nl   = lane & 15;
    const int quad = lane >> 4;
    const long row0 = (long)blockIdx.x * 32;

    const float* xb = x + row0 * D_MODEL;

    const int rbase = w * 2 + (lane >> 5);              // 0..7
    const int sgs   = (lane & 31) ^ (rbase & 7);        // swizzled source sub-granule

#define XSTAGE(buf_, ch_) do {                                                       \
    _Pragma("unroll") for (int p = 0; p < 4; ++p)                                    \
        gload_lds16(xb + (size_t)(p * 8 + rbase) * D_MODEL + (ch_) * 128 + sgs * 4,  \
                    &Xs[buf_][p * 1024 + w * 256]);                                  \
} while (0)

    f32x4 acc[2][3] = {};
    const int nlx = nl & 7;

    XSTAGE(0, 0);
    __syncthreads();

    for (int ch = 0; ch < 8; ++ch) {
        const int buf = ch & 1;
        if (ch < 7) XSTAGE(buf ^ 1, ch + 1);            // async prefetch next chunk
#pragma unroll
        for (int kk = 0; kk < 4; ++kk) {
            const int s0 = kk * 8 + quad * 2;
            const f32x4 fA0 = *(const f32x4*)&Xs[buf][nl * 128 + ((s0) ^ nlx) * 4];
            const f32x4 fA1 = *(const f32x4*)&Xs[buf][nl * 128 + ((s0 + 1) ^ nlx) * 4];
            const f32x4 fB0 = *(const f32x4*)&Xs[buf][(16 + nl) * 128 + ((s0) ^ nlx) * 4];
            const f32x4 fB1 = *(const f32x4*)&Xs[buf][(16 + nl) * 128 + ((s0 + 1) ^ nlx) * 4];
            u32x4 ua, ub;
            ua[0] = cvtpk_bf16(fA0[0], fA0[1]); ua[1] = cvtpk_bf16(fA0[2], fA0[3]);
            ua[2] = cvtpk_bf16(fA1[0], fA1[1]); ua[3] = cvtpk_bf16(fA1[2], fA1[3]);
            ub[0] = cvtpk_bf16(fB0[0], fB0[1]); ub[1] = cvtpk_bf16(fB0[2], fB0[3]);
            ub[2] = cvtpk_bf16(fB1[0], fB1[1]); ub[3] = cvtpk_bf16(fB1[2], fB1[3]);
            const bf16x8 a0 = __builtin_bit_cast(bf16x8, ua);
            const bf16x8 a1 = __builtin_bit_cast(bf16x8, ub);
            const unsigned* wb = Wpk + (size_t)(ch * 16 + kk * 4 + quad) * 768
                                     + (w * 48 + nl) * 4;
#pragma unroll
            for (int t = 0; t < 3; ++t) {
                const bf16x8 b = __builtin_bit_cast(bf16x8, *(const uint4*)(wb + t * 64));
                acc[0][t] = __builtin_amdgcn_mfma_f32_16x16x32_bf16(a0, b, acc[0][t], 0, 0, 0);
                acc[1][t] = __builtin_amdgcn_mfma_f32_16x16x32_bf16(a1, b, acc[1][t], 0, 0, 0);
            }
        }
        __syncthreads();                                // next buf staged + readers done
    }

    const float QSCALE = 0.04508422f;    // D^-0.5 * log2(e): exp2-domain prescale
#pragma unroll
    for (int t = 0; t < 3; ++t) {
        const int n0c = w * 48 + t * 16;
        const int sel = n0c >> 6;
        const int col = (n0c & 63) + nl;
#pragma unroll
        for (int m = 0; m < 2; ++m) {
            if (sel == 0) {
#pragma unroll
                for (int reg = 0; reg < 4; ++reg)
                    Qbf[(row0 + m * 16 + quad * 4 + reg) * D_HEAD + col] =
                        bf16r(acc[m][t][reg] * QSCALE);
            } else if (sel == 1) {
#pragma unroll
                for (int reg = 0; reg < 4; ++reg)
                    Kbf[(row0 + m * 16 + quad * 4 + reg) * D_HEAD + col] =
                        bf16r(acc[m][t][reg]);
            } else {
                uint2 p2;
                p2.x = pk_bf16(acc[m][t][0], acc[m][t][1]);
                p2.y = pk_bf16(acc[m][t][2], acc[m][t][3]);
                *(uint2*)&Vbuf[col * 32 + m * 16 + quad * 4] = p2;
            }
        }
    }
    __syncthreads();
    {
        const int dim  = tid >> 2;
        const int tseg = (tid & 3) * 8;
        const long bb   = row0 >> 12;
        const int tpos0 = (int)(row0 & 4095);
        const uint4 v = *(const uint4*)&Vbuf[dim * 32 + tseg];
        *(uint4*)&Vt[((bb * 64 + dim) << 12) + tpos0 + tseg] = v;
    }
}

// ---------------- MFMA flash attention: R23 — R21 body + fused last-block strip merge -------
// The split-merge round trip (16 MB Po16 to HBM + separate reduce kernel + launch gap,
// ~7 us) is fused: after each wave stores its strip partial, threadfence (release) +
// lane0 atomicAdd(Cnt[strip]); the 8th arriver threadfence-acquires and merges the strip
// in-wave (port of the verified reduce body), writing O directly. Device-scope
// atomics/fences per G16 handle cross-XCD L2 non-coherence. Compute body == R21.
__global__ __launch_bounds__(256, 2) void attn_kernel(
    const u16* __restrict__ Qbf, const u16* __restrict__ Kbf,
    const u16* __restrict__ Vt, u16* __restrict__ Po16, float* __restrict__ Pl,
    unsigned* __restrict__ Cnt, float* __restrict__ O)
{
    __shared__ __align__(16) u16 Kls[2][4096];          // 2 x 64 keys x 64 dims (swizzled)
    __shared__ __align__(16) u16 Pbuf[4][2][16 * 64];   // 16 KB

    const int tid   = threadIdx.x;
    const int w     = tid >> 6;
    const int lane  = tid & 63;
    const int nl    = lane & 15;
    const int quad  = lane >> 4;
    const int gid   = blockIdx.x;                // 0..511
    const int b     = gid & 3;                   // one batch per XCD pair (gid%8 RR)
    const int idx   = gid >> 2;                  // 0..127
    const int sp    = idx & 7;                   // block-uniform K-split 0..7
    const int pair  = idx >> 3;                  // 0..15

    const u16* Kb = Kbf + (size_t)b * T_SEQ * D_HEAD;
    const u16* Vb = Vt  + (size_t)b * D_HEAD * T_SEQ;

    const int qbA = 31 - pair;                   // q-blocks of 128 rows; pair (31-p, p)
    const int qbB = pair;
    const int nA = 2 * qbA + 2;                  // K-tiles needed; nA + nB == 66
    const int nB = 2 * qbB + 2;
    const int cntA = (nA - sp + 7) >> 3;         // sp < 8 <= nA always
    const int ktB0 = sp + SPLIT * cntA - nA;     // in [0,8)
    const int cntB = (ktB0 < nB) ? ((nB - ktB0 + 7) >> 3) : 0;

    // per-lane invariants: stage-source swizzle + ds_read offsets (u16 units)
    const int swz   = ((lane & 7) ^ ((lane >> 3) & 7)) * 8;  // granule XOR, 8 elems each
    const int stgk  = ((lane >> 3) << 6) + swz;              // K: row (lane>>3), 64/row
    const int offh0 = nl * 64 + ((quad ^ (nl & 7)) << 3);
    const int offh1 = nl * 64 + (((quad + 4) ^ (nl & 7)) << 3);
    const int pwsub = ((quad & 1) << 2);
    const int pg0   = (quad >> 1);               // granule contribution from quad

// stage one 64-key K tile into LDS buffer cur_ (wave w issues its 2 of 8 loads)
#define STAGE(cur_, kt_) do {                                                        \
    const int _s0 = (kt_) << 6;                                                      \
    _Pragma("unroll") for (int jj = 0; jj < 2; ++jj) {                               \
        const int j = w * 2 + jj;                                                    \
        gload_lds16(Kb + (size_t)(_s0 + 8 * j) * 64 + stgk, &Kls[cur_][j * 512]);    \
    }                                                                                \
} while (0)

// one K-tile: swapped QK^T (S^T), packed P write, V direct, PV unchanged
#define COMPUTEKV(cur_, kt_) do {                                                    \
    const int _k0 = (kt_) << 6;                                                      \
    uint4 buf[4][2];                                                                 \
    _Pragma("unroll") for (int t = 0; t < 4; ++t) {                                  \
        buf[t][0] = *(const uint4*)&Kls[cur_][t * 1024 + offh0];                     \
        buf[t][1] = *(const uint4*)&Kls[cur_][t * 1024 + offh1];                     \
    }                                                                                \
    f32x4 S[2][4];                                                                   \
    _Pragma("unroll") for (int m = 0; m < 2; ++m)                                    \
    _Pragma("unroll") for (int t = 0; t < 4; ++t) {                                  \
        f32x4 z = {};                                                                \
        z = __builtin_amdgcn_mfma_f32_16x16x32_bf16(                                 \
                __builtin_bit_cast(bf16x8, buf[t][0]), qf[m][0], z, 0, 0, 0);        \
        S[m][t] = __builtin_amdgcn_mfma_f32_16x16x32_bf16(                           \
                __builtin_bit_cast(bf16x8, buf[t][1]), qf[m][1], z, 0, 0, 0);        \
    }                                                                                \
    uint4 vbuf[4][2];   /* direct global; latency hides under softmax below */       \
    _Pragma("unroll") for (int t = 0; t < 4; ++t) {                                  \
        const u16* vp = Vb + (size_t)(t * 16 + nl) * T_SEQ + _k0 + quad * 8;         \
        vbuf[t][0] = *(const uint4*)vp;                                              \
        vbuf[t][1] = *(const uint4*)(vp + 32);                                       \
    }                                                                                \
    _Pragma("unroll") for (int m = 0; m < 2; ++m) {                                  \
        const int _q = wq0 + m * 16 + nl;        /* this lane's q row */             \
        if (_k0 + 63 > wq0 + m * 16) {                                               \
            _Pragma("unroll") for (int t = 0; t < 4; ++t)                            \
            _Pragma("unroll") for (int reg = 0; reg < 4; ++reg)                      \
                if (_k0 + t * 16 + quad * 4 + reg > _q)                              \
                    S[m][t][reg] = -INFINITY;                                        \
        }                                                                            \
        _Pragma("unroll") for (int t = 0; t < 4; ++t)                                \
        _Pragma("unroll") for (int reg = 0; reg < 4; ++reg)                          \
            S[m][t][reg] = exp2f(S[m][t][reg]);                                      \
        float _lm = 0.f;                                                             \
        _Pragma("unroll") for (int t = 0; t < 4; ++t)                                \
            _lm += (S[m][t][0] + S[m][t][1]) + (S[m][t][2] + S[m][t][3]);            \
        l[m] += _lm;                                                                 \
        u16* pb = Pbuf[w][m];                                                        \
        _Pragma("unroll") for (int t = 0; t < 4; ++t) {                              \
            u32x2 pw;                                                                \
            pw[0] = cvtpk_bf16(S[m][t][0], S[m][t][1]);                              \
            pw[1] = cvtpk_bf16(S[m][t][2], S[m][t][3]);                              \
            *(u32x2*)&pb[nl * 64 + (((2 * t + pg0) ^ (nl & 7)) << 3) + pwsub] = pw;  \
        }                                                                            \
    }                                                                                \
    _Pragma("unroll") for (int m = 0; m < 2; ++m) {                                  \
        const u16* pb = Pbuf[w][m];                                                  \
        const bf16x8 pf0 = __builtin_bit_cast(bf16x8,                                \
            *(const uint4*)&pb[nl * 64 + ((quad ^ (nl & 7)) * 8)]);                  \
        const bf16x8 pf1 = __builtin_bit_cast(bf16x8,                                \
            *(const uint4*)&pb[nl * 64 + (((4 + quad) ^ (nl & 7)) * 8)]);            \
        _Pragma("unroll") for (int t = 0; t < 4; ++t) {                              \
            Ot[m][t] = __builtin_amdgcn_mfma_f32_16x16x32_bf16(pf0,                  \
                        __builtin_bit_cast(bf16x8, vbuf[t][0]), Ot[m][t], 0, 0, 0);  \
            Ot[m][t] = __builtin_amdgcn_mfma_f32_16x16x32_bf16(pf1,                  \
                        __builtin_bit_cast(bf16x8, vbuf[t][1]), Ot[m][t], 0, 0, 0);  \
        }                                                                            \
    }                                                                                \
} while (0)

    auto runTile = [&](const int qb, const int kt0, const int cnt) {
        const int wq0 = qb * 128 + w * 32;       // this wave's 32 q-rows

        bf16x8 qf[2][2];
#pragma unroll
        for (int m = 0; m < 2; ++m) {
            const u16* qp = Qbf + ((size_t)b * T_SEQ + wq0 + m * 16 + nl) * D_HEAD + quad * 8;
            qf[m][0] = __builtin_bit_cast(bf16x8, *(const uint4*)qp);
            qf[m][1] = __builtin_bit_cast(bf16x8, *(const uint4*)(qp + 32));
        }

        f32x4 Ot[2][4] = {};
        float l[2] = {0.f, 0.f};

        int kt = kt0;
        if (cnt > 0) STAGE(0, kt);
        __syncthreads();                          // drain stage (vmcnt 0) for all waves
        for (int i = 0; i < cnt; ++i, kt += SPLIT) {
            if (i + 1 < cnt) STAGE((i + 1) & 1, kt + SPLIT);   // async K prefetch, no VGPRs
            COMPUTEKV(i & 1, kt);
            __syncthreads();                      // next buf staged + all readers done
        }

#pragma unroll
        for (int m = 0; m < 2; ++m) {
            float s = l[m];
            s += __shfl_xor(s, 16);               // cross-quad reduce: all quads of q=nl
            s += __shfl_xor(s, 32);
            const int strip = qb * 8 + w * 2 + m;
            const int bs = b * 256 + strip;
            const size_t gr = (size_t)b * T_SEQ + strip * 16;
            u16* po = Po16 + ((size_t)sp * 1024 + bs) * 1024;
#pragma unroll
            for (int t = 0; t < 4; ++t) {
                u32x2 p2;
                p2[0] = pk_bf16(Ot[m][t][0], Ot[m][t][1]);
                p2[1] = pk_bf16(Ot[m][t][2], Ot[m][t][3]);
                __builtin_nontemporal_store(p2, (u32x2*)&po[(t * 16 + nl) * 16 + quad * 4]);
            }
            if (lane < 16)
                __builtin_nontemporal_store(s, &Pl[(size_t)sp * NROWS + gr + nl]);

            // --- fused strip merge: last of the 8 sp-writers folds the partials ---
            __threadfence();                      // release: partials visible device-wide
            unsigned old = 0;
            if (lane == 0) old = atomicAdd(&Cnt[bs], 1u);
            old = (unsigned)__shfl((int)old, 0);
            if (old == 7u) {
                __threadfence();                  // acquire: see all 8 partials
                const int c = lane;               // 0..63: head dim
                float v[16] = {};
                float ls = 0.f;
#pragma unroll
                for (int s2 = 0; s2 < SPLIT; ++s2) {
                    const u16* p = Po16 + ((size_t)s2 * 1024 + bs) * 1024 + c * 16;
                    const u32x4 x0 = *(const u32x4*)p;
                    const u32x4 x1 = *(const u32x4*)(p + 8);
                    const unsigned uu[8] = {x0[0], x0[1], x0[2], x0[3],
                                            x1[0], x1[1], x1[2], x1[3]};
#pragma unroll
                    for (int j = 0; j < 8; ++j) {
                        v[2*j]   += __builtin_bit_cast(float, uu[j] << 16);
                        v[2*j+1] += __builtin_bit_cast(float, uu[j] & 0xFFFF0000u);
                    }
                    if (c < 16) ls += Pl[(size_t)s2 * NROWS + gr + c];
                }
                float inv = (c < 16) ? 1.0f / ls : 0.f;
#pragma unroll
                for (int r = 0; r < 16; ++r)
                    O[(gr + r) * D_HEAD + c] = v[r] * __shfl(inv, r);
            }
        }
    };

    runTile(qbA, sp,   cntA);
    runTile(qbB, ktB0, cntB);

#undef STAGE
#undef COMPUTEKV
}

extern "C" void kernel_launch(void* const* d_in, const int* in_sizes, int n_in,
                              void* d_out, int out_size, void* d_ws, size_t ws_size,
                              hipStream_t stream) {
    const float* x  = (const float*)d_in[0];
    const float* Wq = (const float*)d_in[1];
    const float* Wk = (const float*)d_in[2];
    const float* Wv = (const float*)d_in[3];
    float* out = (float*)d_out;

    const size_t rows = NROWS;                        // 16384
    u16* Qbf = (u16*)d_ws;                            // 2 MB
    u16* Kbf = Qbf + rows * D_HEAD;                   // 2 MB
    u16* Vt  = Kbf + rows * D_HEAD;                   // 2 MB (per-batch transposed [b][h][t])
    unsigned* Wpk = (unsigned*)(Vt + rows * D_HEAD);  // 384 KB
    u16* Po16 = (u16*)(Wpk + 128 * 192 * 4);          // SPLIT*16384*64 bf16 = 16 MB
    float* Pl = (float*)(Po16 + (size_t)SPLIT * rows * D_HEAD);  // 512 KB
    unsigned* Cnt = (unsigned*)(Pl + (size_t)SPLIT * rows);      // 4 KB strip counters

    hipLaunchKernelGGL(packw_kernel, dim3(96), dim3(256), 0, stream,
                       Wq, Wk, Wv, Wpk, Cnt);
    hipLaunchKernelGGL(qkv_kernel, dim3(rows / 32), dim3(256), 0, stream,
                       x, Wpk, Qbf, Kbf, Vt);
    hipLaunchKernelGGL(attn_kernel, dim3(512), dim3(256), 0, stream,
                       Qbf, Kbf, Vt, Po16, Pl, Cnt, out);
}

// Round 14
// 135.138 us; speedup vs baseline: 3.2942x; 3.2942x over previous
//
#include <hip/hip_runtime.h>
#include <hip/hip_bf16.h>

#define D_MODEL 1024
#define D_HEAD  64
#define T_SEQ   4096
#define NB      4
#define NROWS   (NB * T_SEQ)      // 16384
#define SPLIT   8

typedef float f32x4 __attribute__((ext_vector_type(4)));
typedef __bf16 bf16x8 __attribute__((ext_vector_type(8)));
typedef unsigned short u16;
typedef unsigned u32x2 __attribute__((ext_vector_type(2)));
typedef unsigned u32x4 __attribute__((ext_vector_type(4)));

__device__ inline unsigned pk_bf16(float a, float b) {
    unsigned ua = __builtin_bit_cast(unsigned, a);
    unsigned ub = __builtin_bit_cast(unsigned, b);
    ua = (ua + 0x7FFFu + ((ua >> 16) & 1u)) >> 16;   // RNE
    ub = (ub + 0x7FFFu + ((ub >> 16) & 1u)) >> 16;
    return ua | (ub << 16);
}
__device__ inline u16 bf16r(float a) {
    unsigned ua = __builtin_bit_cast(unsigned, a);
    return (u16)((ua + 0x7FFFu + ((ua >> 16) & 1u)) >> 16);
}
// HW packed f32->bf16 (RNE), 1 inst per 2 values; no builtin on gfx950
__device__ inline unsigned cvtpk_bf16(float lo, float hi) {
    unsigned r;
    asm("v_cvt_pk_bf16_f32 %0, %1, %2" : "=v"(r) : "v"(lo), "v"(hi));
    return r;
}

// async global->LDS, 16B per lane, no VGPR staging
__device__ inline void gload_lds16(const void* g, void* l) {
    __builtin_amdgcn_global_load_lds(
        (const __attribute__((address_space(1))) void*)g,
        (__attribute__((address_space(3))) void*)l, 16, 0, 0);
}

// ---------------- W pre-pack: Wpk[kb][n][j] = W_sel[(kb*8+j)*64 + col], bf16 ----------------
__global__ __launch_bounds__(256) void packw_kernel(
    const float* __restrict__ Wq, const float* __restrict__ Wk,
    const float* __restrict__ Wv, unsigned* __restrict__ Wpk)
{
    const int id = blockIdx.x * 256 + threadIdx.x;   // 0..24575
    const int kb = id / 192;
    const int n  = id - kb * 192;
    const int sel = n >> 6, col = n & 63;
    const float* W = sel == 0 ? Wq : (sel == 1 ? Wk : Wv);
    float f[8];
#pragma unroll
    for (int j = 0; j < 8; ++j) f[j] = W[(kb * 8 + j) * 64 + col];
    uint4 o;
    o.x = pk_bf16(f[0], f[1]); o.y = pk_bf16(f[2], f[3]);
    o.z = pk_bf16(f[4], f[5]); o.w = pk_bf16(f[6], f[7]);
    *(uint4*)(Wpk + (size_t)id * 4) = o;
}

// ---------------- QKV projection: R22 — async-DMA f32 staging, cvt-on-read ------------------
__global__ __launch_bounds__(256) void qkv_kernel(
    const float* __restrict__ x, const unsigned* __restrict__ Wpk,
    u16* __restrict__ Qbf, u16* __restrict__ Kbf, u16* __restrict__ Vt)
{
    __shared__ __align__(16) float Xs[2][32 * 128];     // 2 x 16 KB raw f32
    __shared__ __align__(16) u16 Vbuf[64 * 32];         // V^T bounce: [dim 64][tpos 32]

    const int tid  = threadIdx.x;
    const int w    = tid >> 6;
    const int lane = tid & 63;
    const int nl   = lane & 15;
    const int quad = lane >> 4;
    const long row0 = (long)blockIdx.x * 32;

    const float* xb = x + row0 * D_MODEL;

    const int rbase = w * 2 + (lane >> 5);              // 0..7
    const int sgs   = (lane & 31) ^ (rbase & 7);        // swizzled source sub-granule

#define XSTAGE(buf_, ch_) do {                                                       \
    _Pragma("unroll") for (int p = 0; p < 4; ++p)                                    \
        gload_lds16(xb + (size_t)(p * 8 + rbase) * D_MODEL + (ch_) * 128 + sgs * 4,  \
                    &Xs[buf_][p * 1024 + w * 256]);                                  \
} while (0)

    f32x4 acc[2][3] = {};
    const int nlx = nl & 7;

    XSTAGE(0, 0);
    __syncthreads();

    for (int ch = 0; ch < 8; ++ch) {
        const int buf = ch & 1;
        if (ch < 7) XSTAGE(buf ^ 1, ch + 1);            // async prefetch next chunk
#pragma unroll
        for (int kk = 0; kk < 4; ++kk) {
            const int s0 = kk * 8 + quad * 2;
            const f32x4 fA0 = *(const f32x4*)&Xs[buf][nl * 128 + ((s0) ^ nlx) * 4];
            const f32x4 fA1 = *(const f32x4*)&Xs[buf][nl * 128 + ((s0 + 1) ^ nlx) * 4];
            const f32x4 fB0 = *(const f32x4*)&Xs[buf][(16 + nl) * 128 + ((s0) ^ nlx) * 4];
            const f32x4 fB1 = *(const f32x4*)&Xs[buf][(16 + nl) * 128 + ((s0 + 1) ^ nlx) * 4];
            u32x4 ua, ub;
            ua[0] = cvtpk_bf16(fA0[0], fA0[1]); ua[1] = cvtpk_bf16(fA0[2], fA0[3]);
            ua[2] = cvtpk_bf16(fA1[0], fA1[1]); ua[3] = cvtpk_bf16(fA1[2], fA1[3]);
            ub[0] = cvtpk_bf16(fB0[0], fB0[1]); ub[1] = cvtpk_bf16(fB0[2], fB0[3]);
            ub[2] = cvtpk_bf16(fB1[0], fB1[1]); ub[3] = cvtpk_bf16(fB1[2], fB1[3]);
            const bf16x8 a0 = __builtin_bit_cast(bf16x8, ua);
            const bf16x8 a1 = __builtin_bit_cast(bf16x8, ub);
            const unsigned* wb = Wpk + (size_t)(ch * 16 + kk * 4 + quad) * 768
                                     + (w * 48 + nl) * 4;
#pragma unroll
            for (int t = 0; t < 3; ++t) {
                const bf16x8 b = __builtin_bit_cast(bf16x8, *(const uint4*)(wb + t * 64));
                acc[0][t] = __builtin_amdgcn_mfma_f32_16x16x32_bf16(a0, b, acc[0][t], 0, 0, 0);
                acc[1][t] = __builtin_amdgcn_mfma_f32_16x16x32_bf16(a1, b, acc[1][t], 0, 0, 0);
            }
        }
        __syncthreads();                                // next buf staged + readers done
    }

    const float QSCALE = 0.04508422f;    // D^-0.5 * log2(e): exp2-domain prescale
#pragma unroll
    for (int t = 0; t < 3; ++t) {
        const int n0c = w * 48 + t * 16;
        const int sel = n0c >> 6;
        const int col = (n0c & 63) + nl;
#pragma unroll
        for (int m = 0; m < 2; ++m) {
            if (sel == 0) {
#pragma unroll
                for (int reg = 0; reg < 4; ++reg)
                    Qbf[(row0 + m * 16 + quad * 4 + reg) * D_HEAD + col] =
                        bf16r(acc[m][t][reg] * QSCALE);
            } else if (sel == 1) {
#pragma unroll
                for (int reg = 0; reg < 4; ++reg)
                    Kbf[(row0 + m * 16 + quad * 4 + reg) * D_HEAD + col] =
                        bf16r(acc[m][t][reg]);
            } else {
                uint2 p2;
                p2.x = pk_bf16(acc[m][t][0], acc[m][t][1]);
                p2.y = pk_bf16(acc[m][t][2], acc[m][t][3]);
                *(uint2*)&Vbuf[col * 32 + m * 16 + quad * 4] = p2;
            }
        }
    }
    __syncthreads();
    {
        const int dim  = tid >> 2;
        const int tseg = (tid & 3) * 8;
        const long bb   = row0 >> 12;
        const int tpos0 = (int)(row0 & 4095);
        const uint4 v = *(const uint4*)&Vbuf[dim * 32 + tseg];
        *(uint4*)&Vt[((bb * 64 + dim) << 12) + tpos0 + tseg] = v;
    }
}

// ---------------- MFMA flash attention: R21 — swapped QK^T, packed P path (proven) ----------
// R13's fused merge regressed 16x: device-scope __threadfence forces per-XCD L2
// writeback/invalidate (XCDs non-coherent), serializing on the L2 and evicting K/V.
// Reverted to the R12 split-merge form (separate reduce kernel).
__global__ __launch_bounds__(256, 2) void attn_kernel(
    const u16* __restrict__ Qbf, const u16* __restrict__ Kbf,
    const u16* __restrict__ Vt, u16* __restrict__ Po16, float* __restrict__ Pl)
{
    __shared__ __align__(16) u16 Kls[2][4096];          // 2 x 64 keys x 64 dims (swizzled)
    __shared__ __align__(16) u16 Pbuf[4][2][16 * 64];   // 16 KB

    const int tid   = threadIdx.x;
    const int w     = tid >> 6;
    const int lane  = tid & 63;
    const int nl    = lane & 15;
    const int quad  = lane >> 4;
    const int gid   = blockIdx.x;                // 0..511
    const int b     = gid & 3;                   // one batch per XCD pair (gid%8 RR)
    const int idx   = gid >> 2;                  // 0..127
    const int sp    = idx & 7;                   // block-uniform K-split 0..7
    const int pair  = idx >> 3;                  // 0..15

    const u16* Kb = Kbf + (size_t)b * T_SEQ * D_HEAD;
    const u16* Vb = Vt  + (size_t)b * D_HEAD * T_SEQ;

    const int qbA = 31 - pair;                   // q-blocks of 128 rows; pair (31-p, p)
    const int qbB = pair;
    const int nA = 2 * qbA + 2;                  // K-tiles needed; nA + nB == 66
    const int nB = 2 * qbB + 2;
    const int cntA = (nA - sp + 7) >> 3;         // sp < 8 <= nA always
    const int ktB0 = sp + SPLIT * cntA - nA;     // in [0,8)
    const int cntB = (ktB0 < nB) ? ((nB - ktB0 + 7) >> 3) : 0;

    // per-lane invariants: stage-source swizzle + ds_read offsets (u16 units)
    const int swz   = ((lane & 7) ^ ((lane >> 3) & 7)) * 8;  // granule XOR, 8 elems each
    const int stgk  = ((lane >> 3) << 6) + swz;              // K: row (lane>>3), 64/row
    const int offh0 = nl * 64 + ((quad ^ (nl & 7)) << 3);
    const int offh1 = nl * 64 + (((quad + 4) ^ (nl & 7)) << 3);
    // P write base: row q=nl, granule 2t+(quad>>1) XOR (nl&7), sub-offset (quad&1)*4
    const int pwsub = ((quad & 1) << 2);
    const int pg0   = (quad >> 1);               // granule contribution from quad

// stage one 64-key K tile into LDS buffer cur_ (wave w issues its 2 of 8 loads)
#define STAGE(cur_, kt_) do {                                                        \
    const int _s0 = (kt_) << 6;                                                      \
    _Pragma("unroll") for (int jj = 0; jj < 2; ++jj) {                               \
        const int j = w * 2 + jj;                                                    \
        gload_lds16(Kb + (size_t)(_s0 + 8 * j) * 64 + stgk, &Kls[cur_][j * 512]);    \
    }                                                                                \
} while (0)

// one K-tile: swapped QK^T (S^T), packed P write, V direct, PV unchanged
#define COMPUTEKV(cur_, kt_) do {                                                    \
    const int _k0 = (kt_) << 6;                                                      \
    uint4 buf[4][2];                                                                 \
    _Pragma("unroll") for (int t = 0; t < 4; ++t) {                                  \
        buf[t][0] = *(const uint4*)&Kls[cur_][t * 1024 + offh0];                     \
        buf[t][1] = *(const uint4*)&Kls[cur_][t * 1024 + offh1];                     \
    }                                                                                \
    f32x4 S[2][4];                                                                   \
    _Pragma("unroll") for (int m = 0; m < 2; ++m)                                    \
    _Pragma("unroll") for (int t = 0; t < 4; ++t) {                                  \
        f32x4 z = {};                                                                \
        z = __builtin_amdgcn_mfma_f32_16x16x32_bf16(                                 \
                __builtin_bit_cast(bf16x8, buf[t][0]), qf[m][0], z, 0, 0, 0);        \
        S[m][t] = __builtin_amdgcn_mfma_f32_16x16x32_bf16(                           \
                __builtin_bit_cast(bf16x8, buf[t][1]), qf[m][1], z, 0, 0, 0);        \
    }                                                                                \
    uint4 vbuf[4][2];   /* direct global; latency hides under softmax below */       \
    _Pragma("unroll") for (int t = 0; t < 4; ++t) {                                  \
        const u16* vp = Vb + (size_t)(t * 16 + nl) * T_SEQ + _k0 + quad * 8;         \
        vbuf[t][0] = *(const uint4*)vp;                                              \
        vbuf[t][1] = *(const uint4*)(vp + 32);                                       \
    }                                                                                \
    _Pragma("unroll") for (int m = 0; m < 2; ++m) {                                  \
        const int _q = wq0 + m * 16 + nl;        /* this lane's q row */             \
        if (_k0 + 63 > wq0 + m * 16) {                                               \
            _Pragma("unroll") for (int t = 0; t < 4; ++t)                            \
            _Pragma("unroll") for (int reg = 0; reg < 4; ++reg)                      \
                if (_k0 + t * 16 + quad * 4 + reg > _q)                              \
                    S[m][t][reg] = -INFINITY;                                        \
        }                                                                            \
        _Pragma("unroll") for (int t = 0; t < 4; ++t)                                \
        _Pragma("unroll") for (int reg = 0; reg < 4; ++reg)                          \
            S[m][t][reg] = exp2f(S[m][t][reg]);                                      \
        float _lm = 0.f;                                                             \
        _Pragma("unroll") for (int t = 0; t < 4; ++t)                                \
            _lm += (S[m][t][0] + S[m][t][1]) + (S[m][t][2] + S[m][t][3]);            \
        l[m] += _lm;                                                                 \
        u16* pb = Pbuf[w][m];                                                        \
        _Pragma("unroll") for (int t = 0; t < 4; ++t) {                              \
            u32x2 pw;                                                                \
            pw[0] = cvtpk_bf16(S[m][t][0], S[m][t][1]);                              \
            pw[1] = cvtpk_bf16(S[m][t][2], S[m][t][3]);                              \
            *(u32x2*)&pb[nl * 64 + (((2 * t + pg0) ^ (nl & 7)) << 3) + pwsub] = pw;  \
        }                                                                            \
    }                                                                                \
    _Pragma("unroll") for (int m = 0; m < 2; ++m) {                                  \
        const u16* pb = Pbuf[w][m];                                                  \
        const bf16x8 pf0 = __builtin_bit_cast(bf16x8,                                \
            *(const uint4*)&pb[nl * 64 + ((quad ^ (nl & 7)) * 8)]);                  \
        const bf16x8 pf1 = __builtin_bit_cast(bf16x8,                                \
            *(const uint4*)&pb[nl * 64 + (((4 + quad) ^ (nl & 7)) * 8)]);            \
        _Pragma("unroll") for (int t = 0; t < 4; ++t) {                              \
            Ot[m][t] = __builtin_amdgcn_mfma_f32_16x16x32_bf16(pf0,                  \
                        __builtin_bit_cast(bf16x8, vbuf[t][0]), Ot[m][t], 0, 0, 0);  \
            Ot[m][t] = __builtin_amdgcn_mfma_f32_16x16x32_bf16(pf1,                  \
                        __builtin_bit_cast(bf16x8, vbuf[t][1]), Ot[m][t], 0, 0, 0);  \
        }                                                                            \
    }                                                                                \
} while (0)

    auto runTile = [&](const int qb, const int kt0, const int cnt) {
        const int wq0 = qb * 128 + w * 32;       // this wave's 32 q-rows

        bf16x8 qf[2][2];
#pragma unroll
        for (int m = 0; m < 2; ++m) {
            const u16* qp = Qbf + ((size_t)b * T_SEQ + wq0 + m * 16 + nl) * D_HEAD + quad * 8;
            qf[m][0] = __builtin_bit_cast(bf16x8, *(const uint4*)qp);
            qf[m][1] = __builtin_bit_cast(bf16x8, *(const uint4*)(qp + 32));
        }

        f32x4 Ot[2][4] = {};
        float l[2] = {0.f, 0.f};

        int kt = kt0;
        if (cnt > 0) STAGE(0, kt);
        __syncthreads();                          // drain stage (vmcnt 0) for all waves
        for (int i = 0; i < cnt; ++i, kt += SPLIT) {
            if (i + 1 < cnt) STAGE((i + 1) & 1, kt + SPLIT);   // async K prefetch, no VGPRs
            COMPUTEKV(i & 1, kt);
            __syncthreads();                      // next buf staged + all readers done
        }

#pragma unroll
        for (int m = 0; m < 2; ++m) {
            float s = l[m];
            s += __shfl_xor(s, 16);               // cross-quad reduce: all quads of q=nl
            s += __shfl_xor(s, 32);
            const int strip = qb * 8 + w * 2 + m;
            const int bs = b * 256 + strip;
            u16* po = Po16 + ((size_t)sp * 1024 + bs) * 1024;
#pragma unroll
            for (int t = 0; t < 4; ++t) {
                u32x2 p2;
                p2[0] = pk_bf16(Ot[m][t][0], Ot[m][t][1]);
                p2[1] = pk_bf16(Ot[m][t][2], Ot[m][t][3]);
                __builtin_nontemporal_store(p2, (u32x2*)&po[(t * 16 + nl) * 16 + quad * 4]);
            }
            if (lane < 16) {                      // quad==0: one q per lane
                const size_t gr = (size_t)b * T_SEQ + qb * 128 + w * 32 + m * 16;
                __builtin_nontemporal_store(s, &Pl[(size_t)sp * NROWS + gr + nl]);
            }
        }
    };

    runTile(qbA, sp,   cntA);
    runTile(qbB, ktB0, cntB);

#undef STAGE
#undef COMPUTEKV
}

// ---------------- merge K-split partials: O[row][col] = sum_sp Po / sum_sp Pl ---------------
__global__ __launch_bounds__(256) void reduce_kernel(
    const u16* __restrict__ Po16, const float* __restrict__ Pl,
    float* __restrict__ O)
{
    __shared__ float part[4][16][64];    // 16 KB
    __shared__ float lsum[4][16];
    __shared__ float linv[16];
    const int tid = threadIdx.x;
    const int w   = tid >> 6;            // wave = sp-group
    const int c   = tid & 63;            // head dim
    const int bs  = blockIdx.x;
    const int b   = bs >> 8, strip = bs & 255;
    const size_t gr = (size_t)b * T_SEQ + strip * 16;

    float v[16] = {};
    float ls = 0.f;
#pragma unroll
    for (int i = 0; i < 2; ++i) {
        const int sp = w + i * 4;
        const u16* p = Po16 + ((size_t)sp * 1024 + bs) * 1024 + c * 16;
        const u32x4 x0 = __builtin_nontemporal_load((const u32x4*)p);
        const u32x4 x1 = __builtin_nontemporal_load((const u32x4*)p + 1);
        const unsigned uu[8] = {x0[0], x0[1], x0[2], x0[3], x1[0], x1[1], x1[2], x1[3]};
#pragma unroll
        for (int j = 0; j < 8; ++j) {
            v[2*j]   += __builtin_bit_cast(float, uu[j] << 16);
            v[2*j+1] += __builtin_bit_cast(float, uu[j] & 0xFFFF0000u);
        }
        if (c < 16) ls += Pl[(size_t)sp * NROWS + gr + c];
    }
#pragma unroll
    for (int r = 0; r < 16; ++r) part[w][r][c] = v[r];
    if (c < 16) lsum[w][c] = ls;
    __syncthreads();
    if (tid < 16)
        linv[tid] = 1.0f / (lsum[0][tid] + lsum[1][tid] + lsum[2][tid] + lsum[3][tid]);
    __syncthreads();
#pragma unroll
    for (int j = 0; j < 4; ++j) {
        const int r = w + j * 4;
        const float s = (part[0][r][c] + part[1][r][c]) + (part[2][r][c] + part[3][r][c]);
        O[(gr + r) * D_HEAD + c] = s * linv[r];
    }
}

extern "C" void kernel_launch(void* const* d_in, const int* in_sizes, int n_in,
                              void* d_out, int out_size, void* d_ws, size_t ws_size,
                              hipStream_t stream) {
    const float* x  = (const float*)d_in[0];
    const float* Wq = (const float*)d_in[1];
    const float* Wk = (const float*)d_in[2];
    const float* Wv = (const float*)d_in[3];
    float* out = (float*)d_out;

    const size_t rows = NROWS;                        // 16384
    u16* Qbf = (u16*)d_ws;                            // 2 MB
    u16* Kbf = Qbf + rows * D_HEAD;                   // 2 MB
    u16* Vt  = Kbf + rows * D_HEAD;                   // 2 MB (per-batch transposed [b][h][t])
    unsigned* Wpk = (unsigned*)(Vt + rows * D_HEAD);  // 384 KB
    u16* Po16 = (u16*)(Wpk + 128 * 192 * 4);          // SPLIT*16384*64 bf16 = 16 MB
    float* Pl = (float*)(Po16 + (size_t)SPLIT * rows * D_HEAD);  // 512 KB

    hipLaunchKernelGGL(packw_kernel, dim3(96), dim3(256), 0, stream,
                       Wq, Wk, Wv, Wpk);
    hipLaunchKernelGGL(qkv_kernel, dim3(rows / 32), dim3(256), 0, stream,
                       x, Wpk, Qbf, Kbf, Vt);
    hipLaunchKernelGGL(attn_kernel, dim3(512), dim3(256), 0, stream,
                       Qbf, Kbf, Vt, Po16, Pl);
    hipLaunchKernelGGL(reduce_kernel, dim3(NB * 256), dim3(64 * 4), 0, stream,
                       Po16, Pl, out);
}